// Round 5
// baseline (326.048 us; speedup 1.0000x reference)
//
#include <hip/hip_runtime.h>
#include <type_traits>

typedef __attribute__((ext_vector_type(8))) short bf16x8;
typedef __attribute__((ext_vector_type(4))) float f32x4;

static __device__ __forceinline__ unsigned short f2bf(float f) {
    unsigned int u = __float_as_uint(f);
    u += 0x7fffu + ((u >> 16) & 1u);
    return (unsigned short)(u >> 16);
}
// round-half-up: 2 VALU ops; P-values only (|rel err| <= 2^-9, tolerance-safe)
static __device__ __forceinline__ unsigned short f2bf_fast(float f) {
    return (unsigned short)((__float_as_uint(f) + 0x8000u) >> 16);
}

static __device__ __forceinline__ uint4 cvt8(const float* p) {
    f32x4 a = *(const f32x4*)p, b = *(const f32x4*)(p + 4);
    uint4 r; unsigned short* s = (unsigned short*)&r;
    #pragma unroll
    for (int j = 0; j < 4; ++j) { s[j] = f2bf(a[j]); s[j + 4] = f2bf(b[j]); }
    return r;
}

static __device__ __forceinline__ bf16x8 scale8(bf16x8 v, float s) {
    unsigned short r[8];
    #pragma unroll
    for (int j = 0; j < 8; ++j) {
        float f = __uint_as_float(((unsigned int)(unsigned short)v[j]) << 16) * s;
        r[j] = f2bf(f);
    }
    return *(const bf16x8*)r;
}

// async global->LDS, 16B per lane; LDS dest = wave-uniform base + lane*16
static __device__ __forceinline__ void glds16(const unsigned short* g, unsigned short* l) {
    __builtin_amdgcn_global_load_lds(
        (const __attribute__((address_space(1))) unsigned int*)g,
        (__attribute__((address_space(3))) unsigned int*)l, 16, 0, 0);
}

// ---------------------------------------------------------------------------
__global__ __launch_bounds__(256) void cvt_bf16(
    const float* __restrict__ src, unsigned short* __restrict__ dst, int n8)
{
    int i = blockIdx.x * 256 + threadIdx.x;
    if (i < n8) *(uint4*)&dst[(size_t)i * 8] = cvt8(&src[(size_t)i * 8]);
}

// ---------------------------------------------------------------------------
__global__ __launch_bounds__(256) void transpose_cvt(
    const float* __restrict__ src, unsigned short* __restrict__ dst, int R, int C)
{
    __shared__ unsigned short t[64 * 72];
    const int r0 = blockIdx.y * 64, c0 = blockIdx.x * 64;
    const int tid = threadIdx.x;
    #pragma unroll
    for (int i = 0; i < 4; ++i) {
        int idx = tid + i * 256;
        int row = idx >> 4, seg = idx & 15;
        f32x4 v = *(const f32x4*)&src[(size_t)(r0 + row) * C + c0 + seg * 4];
        #pragma unroll
        for (int j = 0; j < 4; ++j) t[row * 72 + seg * 4 + j] = f2bf(v[j]);
    }
    __syncthreads();
    #pragma unroll
    for (int i = 0; i < 2; ++i) {
        int idx = tid + i * 256;
        int row = idx >> 3, seg = idx & 7;
        uint4 tv; unsigned short* tmp = (unsigned short*)&tv;
        #pragma unroll
        for (int j = 0; j < 8; ++j) tmp[j] = t[(seg * 8 + j) * 72 + row];
        *(uint4*)&dst[(size_t)(c0 + row) * R + r0 + seg * 8] = tv;
    }
}

// ---------------------------------------------------------------------------
// V^T precompute: vt[bh][hd=64][L=2048] from qkv_ws V-part (bf16).
// ---------------------------------------------------------------------------
__global__ __launch_bounds__(256) void transpose_v(
    const unsigned short* __restrict__ qkv, unsigned short* __restrict__ vt)
{
    __shared__ unsigned short t[64 * 72];
    const int lt = blockIdx.x, bh = blockIdx.y, b = bh >> 4, h = bh & 15;
    const int tid = threadIdx.x;
    #pragma unroll
    for (int i = 0; i < 2; ++i) {
        int idx = tid + i * 256, row = idx >> 3, seg = idx & 7;
        *(uint4*)&t[row * 72 + seg * 8] =
            *(const uint4*)&qkv[(size_t)(b * 2048 + lt * 64 + row) * 3072 + 2048 + h * 64 + seg * 8];
    }
    __syncthreads();
    #pragma unroll
    for (int i = 0; i < 2; ++i) {
        int idx = tid + i * 256, row = idx >> 3, seg = idx & 7;
        uint4 tv; unsigned short* tmp = (unsigned short*)&tv;
        #pragma unroll
        for (int j = 0; j < 8; ++j) tmp[j] = t[(seg * 8 + j) * 72 + row];
        *(uint4*)&vt[((size_t)bh * 64 + row) * 2048 + lt * 64 + seg * 8] = tv;
    }
}

// ---------------------------------------------------------------------------
// m97-pattern GEMM: C = A[M][K] * Bt[N][K]^T, bf16 in, global_load_lds staging.
// ---------------------------------------------------------------------------
template <typename OT>
__global__ __launch_bounds__(256) void gemm_lds(
    const unsigned short* __restrict__ A, const unsigned short* __restrict__ Bt,
    OT* __restrict__ C, int M, int N, int K)
{
    __shared__ unsigned short As[128 * 32];
    __shared__ unsigned short Bs[128 * 32];
    const int tid = threadIdx.x;
    const int wave = tid >> 6, lane = tid & 63, quad = lane >> 4, l16 = lane & 15;
    const int wr = (wave >> 1) * 64, wc = (wave & 1) * 64;
    const int m0 = blockIdx.y * 128, n0 = blockIdx.x * 128;

    const unsigned short* ga = A  + (size_t)(m0 + wave * 32 + (lane >> 2)) * K + (lane & 3) * 8;
    const unsigned short* gb = Bt + (size_t)(n0 + wave * 32 + (lane >> 2)) * K + (lane & 3) * 8;
    unsigned short* la = &As[wave * 32 * 32];
    unsigned short* lb = &Bs[wave * 32 * 32];
    const size_t step16 = (size_t)16 * K;

    f32x4 acc[4][4];
    #pragma unroll
    for (int i = 0; i < 4; ++i)
        #pragma unroll
        for (int j = 0; j < 4; ++j) acc[i][j] = (f32x4){0.f, 0.f, 0.f, 0.f};

    for (int kt = 0; kt < K; kt += 32) {
        glds16(ga, la);
        glds16(ga + step16, la + 512);
        glds16(gb, lb);
        glds16(gb + step16, lb + 512);
        ga += 32; gb += 32;
        __syncthreads();
        bf16x8 af[4], bf[4];
        #pragma unroll
        for (int i = 0; i < 4; ++i) {
            af[i] = *(const bf16x8*)&As[(wr + i * 16 + l16) * 32 + quad * 8];
            bf[i] = *(const bf16x8*)&Bs[(wc + i * 16 + l16) * 32 + quad * 8];
        }
        #pragma unroll
        for (int mi = 0; mi < 4; ++mi)
            #pragma unroll
            for (int ni = 0; ni < 4; ++ni)
                acc[mi][ni] = __builtin_amdgcn_mfma_f32_16x16x32_bf16(
                    af[mi], bf[ni], acc[mi][ni], 0, 0, 0);
        __syncthreads();
    }
    #pragma unroll
    for (int mi = 0; mi < 4; ++mi)
        #pragma unroll
        for (int ni = 0; ni < 4; ++ni)
            #pragma unroll
            for (int r = 0; r < 4; ++r) {
                int row = m0 + wr + mi * 16 + quad * 4 + r;
                int col = n0 + wc + ni * 16 + l16;
                if constexpr (std::is_same_v<OT, float>)
                    C[(size_t)row * N + col] = acc[mi][ni][r];
                else
                    C[(size_t)row * N + col] = f2bf(acc[mi][ni][r]);
            }
}

// ---------------------------------------------------------------------------
// Dual-score causal flash attention.  64-row q-tiles -> 1024 blocks, 36.9 KB
// LDS -> 4 blocks/CU, ALL blocks resident (max independent chains).
// Fixed-base softmax (m=0): scores/(ln L*T*sqrt(hd)) are O(1).
// grid = (32 bh, 32 qt); qt descending so heavy tiles dispatch first.
// ---------------------------------------------------------------------------
__global__ __launch_bounds__(256) void attn4(
    const unsigned short* __restrict__ qkv, const float* __restrict__ qg,
    const unsigned short* __restrict__ kgb, const unsigned short* __restrict__ vt,
    unsigned short* __restrict__ y)
{
    const int L = 2048, D3 = 3072, Dm = 1024;
    const float SC2 = 0.125f * 1.44269504088896f / 7.6246189861593985f; // log2-domain

    const int qt = 31 - (int)blockIdx.y;
    const int bh = blockIdx.x, b = bh >> 4, h = bh & 15;
    const int tid = threadIdx.x, wave = tid >> 6, lane = tid & 63;
    const int quad = lane >> 4, l16 = lane & 15;

    // [chunk(2)][row(64)][32+4pad] -> conflict-light, 9216 B each
    __shared__ unsigned short K_l[2 * 2304];
    __shared__ unsigned short G_l[2 * 2304];
    __shared__ unsigned short V_l[2 * 2304];   // [keychunk][hd][keys32]
    __shared__ unsigned short P_l[4 * 1152];   // per-wave [16][72]
    unsigned short* Pw = &P_l[wave * 1152];

    // Q / Qg fragments pre-scaled by SC2
    bf16x8 qf[2], gf[2];
    {
        const int qrow = qt * 64 + wave * 16 + l16;
        const unsigned short* qp = qkv + (size_t)(b * L + qrow) * D3 + h * 64;
        const float* gp = qg + (size_t)(b * L + qrow) * Dm + h * 64;
        #pragma unroll
        for (int c = 0; c < 2; ++c) {
            qf[c] = scale8(*(const bf16x8*)(qp + c * 32 + quad * 8), SC2);
            uint4 t = cvt8(gp + c * 32 + quad * 8);
            gf[c] = scale8(*(const bf16x8*)&t, SC2);
        }
    }

    f32x4 o[4];
    #pragma unroll
    for (int nd = 0; nd < 4; ++nd) o[nd] = (f32x4){0.f, 0.f, 0.f, 0.f};
    float lsum[4];
    #pragma unroll
    for (int r = 0; r < 4; ++r) lsum[r] = 0.f;

    const int ktmax = qt;
    const int prow = tid >> 3, pseg = tid & 7;
    const int pc = pseg >> 2, ps4 = pseg & 3;

    uint4 pk[2], pg[2], pv[2];
    #pragma unroll
    for (int i = 0; i < 2; ++i) {   // prefetch tile 0
        int row = prow + i * 32;
        size_t gr = (size_t)(b * L + row);
        pk[i] = *(const uint4*)&qkv[gr * D3 + 1024 + h * 64 + pseg * 8];
        pg[i] = *(const uint4*)&kgb[gr * Dm + h * 64 + pseg * 8];
        pv[i] = *(const uint4*)&vt[((size_t)bh * 64 + row) * L + pseg * 8];
    }

    for (int kt = 0; kt <= ktmax; ++kt) {
        __syncthreads();                       // prev tile's LDS reads done
        #pragma unroll
        for (int i = 0; i < 2; ++i) {
            int row = prow + i * 32;
            int off = pc * 2304 + row * 36 + ps4 * 8;
            *(uint4*)&K_l[off] = pk[i];
            *(uint4*)&G_l[off] = pg[i];
            *(uint4*)&V_l[off] = pv[i];
        }
        __syncthreads();
        if (kt < ktmax) {                      // overlap next tile's loads w/ compute
            #pragma unroll
            for (int i = 0; i < 2; ++i) {
                int row = prow + i * 32;
                size_t gr = (size_t)(b * L + (kt + 1) * 64 + row);
                pk[i] = *(const uint4*)&qkv[gr * D3 + 1024 + h * 64 + pseg * 8];
                pg[i] = *(const uint4*)&kgb[gr * Dm + h * 64 + pseg * 8];
                pv[i] = *(const uint4*)&vt[((size_t)bh * 64 + row) * L + (kt + 1) * 64 + pseg * 8];
            }
        }

        // ---- S = (Q K^T + Qg Kg^T), scale pre-folded ----
        f32x4 s[4];
        #pragma unroll
        for (int ni = 0; ni < 4; ++ni) {
            bf16x8 kf0 = *(const bf16x8*)&K_l[(ni * 16 + l16) * 36 + quad * 8];
            bf16x8 kf1 = *(const bf16x8*)&K_l[2304 + (ni * 16 + l16) * 36 + quad * 8];
            bf16x8 gb0 = *(const bf16x8*)&G_l[(ni * 16 + l16) * 36 + quad * 8];
            bf16x8 gb1 = *(const bf16x8*)&G_l[2304 + (ni * 16 + l16) * 36 + quad * 8];
            f32x4 a = (f32x4){0.f, 0.f, 0.f, 0.f};
            a = __builtin_amdgcn_mfma_f32_16x16x32_bf16(qf[0], kf0, a, 0, 0, 0);
            a = __builtin_amdgcn_mfma_f32_16x16x32_bf16(gf[0], gb0, a, 0, 0, 0);
            a = __builtin_amdgcn_mfma_f32_16x16x32_bf16(qf[1], kf1, a, 0, 0, 0);
            a = __builtin_amdgcn_mfma_f32_16x16x32_bf16(gf[1], gb1, a, 0, 0, 0);
            s[ni] = a;
        }

        // ---- fixed-base exp + causal mask; lane-partial row sums ----
        {
            const int rowbase = qt * 64 + wave * 16 + quad * 4;
            const bool safe = (kt * 64 + 63 <= rowbase);
            #pragma unroll
            for (int ni = 0; ni < 4; ++ni) {
                const int key = kt * 64 + ni * 16 + l16;
                #pragma unroll
                for (int r = 0; r < 4; ++r) {
                    float e = (safe || key <= rowbase + r) ? exp2f(s[ni][r]) : 0.f;
                    lsum[r] += e;
                    Pw[(quad * 4 + r) * 72 + ni * 16 + l16] = f2bf_fast(e);
                }
            }
        }
        asm volatile("s_waitcnt lgkmcnt(0)" ::: "memory");  // P visible to own wave

        // ---- O += P V ----
        bf16x8 pa[2];
        #pragma unroll
        for (int c = 0; c < 2; ++c)
            pa[c] = *(const bf16x8*)&Pw[l16 * 72 + c * 32 + quad * 8];
        #pragma unroll
        for (int nd = 0; nd < 4; ++nd) {
            bf16x8 vf0 = *(const bf16x8*)&V_l[(nd * 16 + l16) * 36 + quad * 8];
            bf16x8 vf1 = *(const bf16x8*)&V_l[2304 + (nd * 16 + l16) * 36 + quad * 8];
            o[nd] = __builtin_amdgcn_mfma_f32_16x16x32_bf16(pa[0], vf0, o[nd], 0, 0, 0);
            o[nd] = __builtin_amdgcn_mfma_f32_16x16x32_bf16(pa[1], vf1, o[nd], 0, 0, 0);
        }
    }

    // ---- one-time row-sum reduce + normalize + write ----
    #pragma unroll
    for (int r = 0; r < 4; ++r) {
        float rs = lsum[r];
        #pragma unroll
        for (int off = 1; off < 16; off <<= 1) rs += __shfl_xor(rs, off);
        float inv = 1.f / rs;
        int row = qt * 64 + wave * 16 + quad * 4 + r;
        #pragma unroll
        for (int nd = 0; nd < 4; ++nd)
            y[(size_t)(b * L + row) * Dm + h * 64 + nd * 16 + l16] =
                f2bf(o[nd][r] * inv);
    }
}

// ---------------------------------------------------------------------------
extern "C" void kernel_launch(void* const* d_in, const int* in_sizes, int n_in,
                              void* d_out, int out_size, void* d_ws, size_t ws_size,
                              hipStream_t stream) {
    const float* x     = (const float*)d_in[0];
    const float* q_g   = (const float*)d_in[1];
    const float* k_g   = (const float*)d_in[2];
    const float* W_qkv = (const float*)d_in[3];
    const float* W_out = (const float*)d_in[4];
    float* out = (float*)d_out;
    unsigned short* ws = (unsigned short*)d_ws;

    unsigned short* qkv_ws = ws;                 // [4096][3072]
    unsigned short* y_ws   = ws + 12582912;      // [4096][1024]
    unsigned short* wtq    = ws + 16777216;      // [3072][1024]
    unsigned short* wto    = ws + 19922944;      // [1024][1024]
    unsigned short* kg_bf  = ws + 20971520;      // [4096][1024]
    unsigned short* x_bf   = ws + 25165824;      // [4096][1024]; dead after gemm1
    unsigned short* vt_bf  = x_bf;               // alias: [32][64][2048]

    dim3 blk(256);
    cvt_bf16<<<2048, blk, 0, stream>>>(x,   x_bf,  524288);
    cvt_bf16<<<2048, blk, 0, stream>>>(k_g, kg_bf, 524288);
    transpose_cvt<<<dim3(48, 16), blk, 0, stream>>>(W_qkv, wtq, 1024, 3072);
    transpose_cvt<<<dim3(16, 16), blk, 0, stream>>>(W_out, wto, 1024, 1024);
    gemm_lds<unsigned short><<<dim3(24, 32), blk, 0, stream>>>(
        x_bf, wtq, qkv_ws, 4096, 3072, 1024);
    transpose_v<<<dim3(32, 32), blk, 0, stream>>>(qkv_ws, vt_bf);
    attn4<<<dim3(32, 32), blk, 0, stream>>>(qkv_ws, q_g, kg_bf, vt_bf, y_ws);
    gemm_lds<float><<<dim3(8, 32), blk, 0, stream>>>(
        y_ws, wto, out, 4096, 1024, 1024);
}

// Round 6
// 324.143 us; speedup vs baseline: 1.0059x; 1.0059x over previous
//
#include <hip/hip_runtime.h>
#include <type_traits>

typedef __attribute__((ext_vector_type(8))) short bf16x8;
typedef __attribute__((ext_vector_type(4))) float f32x4;

static __device__ __forceinline__ unsigned short f2bf(float f) {
    unsigned int u = __float_as_uint(f);
    u += 0x7fffu + ((u >> 16) & 1u);
    return (unsigned short)(u >> 16);
}
// round-half-up: 2 VALU ops; P-values only (|rel err| <= 2^-9, tolerance-safe)
static __device__ __forceinline__ unsigned short f2bf_fast(float f) {
    return (unsigned short)((__float_as_uint(f) + 0x8000u) >> 16);
}

static __device__ __forceinline__ uint4 cvt8(const float* p) {
    f32x4 a = *(const f32x4*)p, b = *(const f32x4*)(p + 4);
    uint4 r; unsigned short* s = (unsigned short*)&r;
    #pragma unroll
    for (int j = 0; j < 4; ++j) { s[j] = f2bf(a[j]); s[j + 4] = f2bf(b[j]); }
    return r;
}

static __device__ __forceinline__ bf16x8 scale8(bf16x8 v, float s) {
    unsigned short r[8];
    #pragma unroll
    for (int j = 0; j < 8; ++j) {
        float f = __uint_as_float(((unsigned int)(unsigned short)v[j]) << 16) * s;
        r[j] = f2bf(f);
    }
    return *(const bf16x8*)r;
}

// async global->LDS, 16B per lane; LDS dest = wave-uniform base + lane*16
static __device__ __forceinline__ void glds16(const unsigned short* g, unsigned short* l) {
    __builtin_amdgcn_global_load_lds(
        (const __attribute__((address_space(1))) unsigned int*)g,
        (__attribute__((address_space(3))) unsigned int*)l, 16, 0, 0);
}

// ---------------------------------------------------------------------------
__global__ __launch_bounds__(256) void cvt_bf16(
    const float* __restrict__ src, unsigned short* __restrict__ dst, int n8)
{
    int i = blockIdx.x * 256 + threadIdx.x;
    if (i < n8) *(uint4*)&dst[(size_t)i * 8] = cvt8(&src[(size_t)i * 8]);
}

// ---------------------------------------------------------------------------
__global__ __launch_bounds__(256) void transpose_cvt(
    const float* __restrict__ src, unsigned short* __restrict__ dst, int R, int C)
{
    __shared__ unsigned short t[64 * 72];
    const int r0 = blockIdx.y * 64, c0 = blockIdx.x * 64;
    const int tid = threadIdx.x;
    #pragma unroll
    for (int i = 0; i < 4; ++i) {
        int idx = tid + i * 256;
        int row = idx >> 4, seg = idx & 15;
        f32x4 v = *(const f32x4*)&src[(size_t)(r0 + row) * C + c0 + seg * 4];
        #pragma unroll
        for (int j = 0; j < 4; ++j) t[row * 72 + seg * 4 + j] = f2bf(v[j]);
    }
    __syncthreads();
    #pragma unroll
    for (int i = 0; i < 2; ++i) {
        int idx = tid + i * 256;
        int row = idx >> 3, seg = idx & 7;
        uint4 tv; unsigned short* tmp = (unsigned short*)&tv;
        #pragma unroll
        for (int j = 0; j < 8; ++j) tmp[j] = t[(seg * 8 + j) * 72 + row];
        *(uint4*)&dst[(size_t)(c0 + row) * R + r0 + seg * 8] = tv;
    }
}

// ---------------------------------------------------------------------------
// V^T precompute: vt[bh][hd=64][L=2048] from qkv_ws V-part (bf16).
// ---------------------------------------------------------------------------
__global__ __launch_bounds__(256) void transpose_v(
    const unsigned short* __restrict__ qkv, unsigned short* __restrict__ vt)
{
    __shared__ unsigned short t[64 * 72];
    const int lt = blockIdx.x, bh = blockIdx.y, b = bh >> 4, h = bh & 15;
    const int tid = threadIdx.x;
    #pragma unroll
    for (int i = 0; i < 2; ++i) {
        int idx = tid + i * 256, row = idx >> 3, seg = idx & 7;
        *(uint4*)&t[row * 72 + seg * 8] =
            *(const uint4*)&qkv[(size_t)(b * 2048 + lt * 64 + row) * 3072 + 2048 + h * 64 + seg * 8];
    }
    __syncthreads();
    #pragma unroll
    for (int i = 0; i < 2; ++i) {
        int idx = tid + i * 256, row = idx >> 3, seg = idx & 7;
        uint4 tv; unsigned short* tmp = (unsigned short*)&tv;
        #pragma unroll
        for (int j = 0; j < 8; ++j) tmp[j] = t[(seg * 8 + j) * 72 + row];
        *(uint4*)&vt[((size_t)bh * 64 + row) * 2048 + lt * 64 + seg * 8] = tv;
    }
}

// ---------------------------------------------------------------------------
// m97-pattern GEMM: C = A[M][K] * Bt[N][K]^T, bf16 in, global_load_lds staging.
// ---------------------------------------------------------------------------
template <typename OT>
__global__ __launch_bounds__(256) void gemm_lds(
    const unsigned short* __restrict__ A, const unsigned short* __restrict__ Bt,
    OT* __restrict__ C, int M, int N, int K)
{
    __shared__ unsigned short As[128 * 32];
    __shared__ unsigned short Bs[128 * 32];
    const int tid = threadIdx.x;
    const int wave = tid >> 6, lane = tid & 63, quad = lane >> 4, l16 = lane & 15;
    const int wr = (wave >> 1) * 64, wc = (wave & 1) * 64;
    const int m0 = blockIdx.y * 128, n0 = blockIdx.x * 128;

    const unsigned short* ga = A  + (size_t)(m0 + wave * 32 + (lane >> 2)) * K + (lane & 3) * 8;
    const unsigned short* gb = Bt + (size_t)(n0 + wave * 32 + (lane >> 2)) * K + (lane & 3) * 8;
    unsigned short* la = &As[wave * 32 * 32];
    unsigned short* lb = &Bs[wave * 32 * 32];
    const size_t step16 = (size_t)16 * K;

    f32x4 acc[4][4];
    #pragma unroll
    for (int i = 0; i < 4; ++i)
        #pragma unroll
        for (int j = 0; j < 4; ++j) acc[i][j] = (f32x4){0.f, 0.f, 0.f, 0.f};

    for (int kt = 0; kt < K; kt += 32) {
        glds16(ga, la);
        glds16(ga + step16, la + 512);
        glds16(gb, lb);
        glds16(gb + step16, lb + 512);
        ga += 32; gb += 32;
        __syncthreads();
        bf16x8 af[4], bf[4];
        #pragma unroll
        for (int i = 0; i < 4; ++i) {
            af[i] = *(const bf16x8*)&As[(wr + i * 16 + l16) * 32 + quad * 8];
            bf[i] = *(const bf16x8*)&Bs[(wc + i * 16 + l16) * 32 + quad * 8];
        }
        #pragma unroll
        for (int mi = 0; mi < 4; ++mi)
            #pragma unroll
            for (int ni = 0; ni < 4; ++ni)
                acc[mi][ni] = __builtin_amdgcn_mfma_f32_16x16x32_bf16(
                    af[mi], bf[ni], acc[mi][ni], 0, 0, 0);
        __syncthreads();
    }
    #pragma unroll
    for (int mi = 0; mi < 4; ++mi)
        #pragma unroll
        for (int ni = 0; ni < 4; ++ni)
            #pragma unroll
            for (int r = 0; r < 4; ++r) {
                int row = m0 + wr + mi * 16 + quad * 4 + r;
                int col = n0 + wc + ni * 16 + l16;
                if constexpr (std::is_same_v<OT, float>)
                    C[(size_t)row * N + col] = acc[mi][ni][r];
                else
                    C[(size_t)row * N + col] = f2bf(acc[mi][ni][r]);
            }
}

// ---------------------------------------------------------------------------
// Dual-score causal flash attention.  64-row q-tiles, 1024 blocks, 36.9 KB
// LDS -> 4 blocks/CU (16 waves/CU).  __launch_bounds__(256,4) matches that
// occupancy exactly -> ~128 VGPR budget, NO scratch spills (round-5 lesson:
// default budget chose 64 VGPR and spilled 300 MB to scratch).
// Fixed-base softmax (m=0): scores/(ln L*T*sqrt(hd)) are O(1).
// ---------------------------------------------------------------------------
__global__ __launch_bounds__(256, 4) void attn4(
    const unsigned short* __restrict__ qkv, const float* __restrict__ qg,
    const unsigned short* __restrict__ kgb, const unsigned short* __restrict__ vt,
    unsigned short* __restrict__ y)
{
    const int L = 2048, D3 = 3072, Dm = 1024;
    const float SC2 = 0.125f * 1.44269504088896f / 7.6246189861593985f; // log2-domain

    const int qt = 31 - (int)blockIdx.y;
    const int bh = blockIdx.x, b = bh >> 4, h = bh & 15;
    const int tid = threadIdx.x, wave = tid >> 6, lane = tid & 63;
    const int quad = lane >> 4, l16 = lane & 15;

    // [chunk(2)][row(64)][32+4pad] -> conflict-light, 9216 B each
    __shared__ unsigned short K_l[2 * 2304];
    __shared__ unsigned short G_l[2 * 2304];
    __shared__ unsigned short V_l[2 * 2304];   // [keychunk][hd][keys32]
    __shared__ unsigned short P_l[4 * 1152];   // per-wave [16][72]
    unsigned short* Pw = &P_l[wave * 1152];

    // Q / Qg fragments pre-scaled by SC2
    bf16x8 qf[2], gf[2];
    {
        const int qrow = qt * 64 + wave * 16 + l16;
        const unsigned short* qp = qkv + (size_t)(b * L + qrow) * D3 + h * 64;
        const float* gp = qg + (size_t)(b * L + qrow) * Dm + h * 64;
        #pragma unroll
        for (int c = 0; c < 2; ++c) {
            qf[c] = scale8(*(const bf16x8*)(qp + c * 32 + quad * 8), SC2);
            uint4 t = cvt8(gp + c * 32 + quad * 8);
            gf[c] = scale8(*(const bf16x8*)&t, SC2);
        }
    }

    f32x4 o[4];
    #pragma unroll
    for (int nd = 0; nd < 4; ++nd) o[nd] = (f32x4){0.f, 0.f, 0.f, 0.f};
    float lsum[4];
    #pragma unroll
    for (int r = 0; r < 4; ++r) lsum[r] = 0.f;

    const int ktmax = qt;
    const int prow = tid >> 3, pseg = tid & 7;
    const int pc = pseg >> 2, ps4 = pseg & 3;

    uint4 pk[2], pg[2], pv[2];
    #pragma unroll
    for (int i = 0; i < 2; ++i) {   // prefetch tile 0
        int row = prow + i * 32;
        size_t gr = (size_t)(b * L + row);
        pk[i] = *(const uint4*)&qkv[gr * D3 + 1024 + h * 64 + pseg * 8];
        pg[i] = *(const uint4*)&kgb[gr * Dm + h * 64 + pseg * 8];
        pv[i] = *(const uint4*)&vt[((size_t)bh * 64 + row) * L + pseg * 8];
    }

    for (int kt = 0; kt <= ktmax; ++kt) {
        __syncthreads();                       // prev tile's LDS reads done
        #pragma unroll
        for (int i = 0; i < 2; ++i) {
            int row = prow + i * 32;
            int off = pc * 2304 + row * 36 + ps4 * 8;
            *(uint4*)&K_l[off] = pk[i];
            *(uint4*)&G_l[off] = pg[i];
            *(uint4*)&V_l[off] = pv[i];
        }
        __syncthreads();
        if (kt < ktmax) {                      // overlap next tile's loads w/ compute
            #pragma unroll
            for (int i = 0; i < 2; ++i) {
                int row = prow + i * 32;
                size_t gr = (size_t)(b * L + (kt + 1) * 64 + row);
                pk[i] = *(const uint4*)&qkv[gr * D3 + 1024 + h * 64 + pseg * 8];
                pg[i] = *(const uint4*)&kgb[gr * Dm + h * 64 + pseg * 8];
                pv[i] = *(const uint4*)&vt[((size_t)bh * 64 + row) * L + (kt + 1) * 64 + pseg * 8];
            }
        }

        // ---- S = (Q K^T + Qg Kg^T), scale pre-folded ----
        f32x4 s[4];
        #pragma unroll
        for (int ni = 0; ni < 4; ++ni) {
            bf16x8 kf0 = *(const bf16x8*)&K_l[(ni * 16 + l16) * 36 + quad * 8];
            bf16x8 kf1 = *(const bf16x8*)&K_l[2304 + (ni * 16 + l16) * 36 + quad * 8];
            bf16x8 gb0 = *(const bf16x8*)&G_l[(ni * 16 + l16) * 36 + quad * 8];
            bf16x8 gb1 = *(const bf16x8*)&G_l[2304 + (ni * 16 + l16) * 36 + quad * 8];
            f32x4 a = (f32x4){0.f, 0.f, 0.f, 0.f};
            a = __builtin_amdgcn_mfma_f32_16x16x32_bf16(qf[0], kf0, a, 0, 0, 0);
            a = __builtin_amdgcn_mfma_f32_16x16x32_bf16(gf[0], gb0, a, 0, 0, 0);
            a = __builtin_amdgcn_mfma_f32_16x16x32_bf16(qf[1], kf1, a, 0, 0, 0);
            a = __builtin_amdgcn_mfma_f32_16x16x32_bf16(gf[1], gb1, a, 0, 0, 0);
            s[ni] = a;
        }

        // ---- fixed-base exp + causal mask; lane-partial row sums ----
        {
            const int rowbase = qt * 64 + wave * 16 + quad * 4;
            const bool safe = (kt * 64 + 63 <= rowbase);
            #pragma unroll
            for (int ni = 0; ni < 4; ++ni) {
                const int key = kt * 64 + ni * 16 + l16;
                #pragma unroll
                for (int r = 0; r < 4; ++r) {
                    float e = (safe || key <= rowbase + r) ? exp2f(s[ni][r]) : 0.f;
                    lsum[r] += e;
                    Pw[(quad * 4 + r) * 72 + ni * 16 + l16] = f2bf_fast(e);
                }
            }
        }
        asm volatile("s_waitcnt lgkmcnt(0)" ::: "memory");  // P visible to own wave

        // ---- O += P V ----
        bf16x8 pa[2];
        #pragma unroll
        for (int c = 0; c < 2; ++c)
            pa[c] = *(const bf16x8*)&Pw[l16 * 72 + c * 32 + quad * 8];
        #pragma unroll
        for (int nd = 0; nd < 4; ++nd) {
            bf16x8 vf0 = *(const bf16x8*)&V_l[(nd * 16 + l16) * 36 + quad * 8];
            bf16x8 vf1 = *(const bf16x8*)&V_l[2304 + (nd * 16 + l16) * 36 + quad * 8];
            o[nd] = __builtin_amdgcn_mfma_f32_16x16x32_bf16(pa[0], vf0, o[nd], 0, 0, 0);
            o[nd] = __builtin_amdgcn_mfma_f32_16x16x32_bf16(pa[1], vf1, o[nd], 0, 0, 0);
        }
    }

    // ---- one-time row-sum reduce + normalize + write ----
    #pragma unroll
    for (int r = 0; r < 4; ++r) {
        float rs = lsum[r];
        #pragma unroll
        for (int off = 1; off < 16; off <<= 1) rs += __shfl_xor(rs, off);
        float inv = 1.f / rs;
        int row = qt * 64 + wave * 16 + quad * 4 + r;
        #pragma unroll
        for (int nd = 0; nd < 4; ++nd)
            y[(size_t)(b * L + row) * Dm + h * 64 + nd * 16 + l16] =
                f2bf(o[nd][r] * inv);
    }
}

// ---------------------------------------------------------------------------
extern "C" void kernel_launch(void* const* d_in, const int* in_sizes, int n_in,
                              void* d_out, int out_size, void* d_ws, size_t ws_size,
                              hipStream_t stream) {
    const float* x     = (const float*)d_in[0];
    const float* q_g   = (const float*)d_in[1];
    const float* k_g   = (const float*)d_in[2];
    const float* W_qkv = (const float*)d_in[3];
    const float* W_out = (const float*)d_in[4];
    float* out = (float*)d_out;
    unsigned short* ws = (unsigned short*)d_ws;

    unsigned short* qkv_ws = ws;                 // [4096][3072]
    unsigned short* y_ws   = ws + 12582912;      // [4096][1024]
    unsigned short* wtq    = ws + 16777216;      // [3072][1024]
    unsigned short* wto    = ws + 19922944;      // [1024][1024]
    unsigned short* kg_bf  = ws + 20971520;      // [4096][1024]
    unsigned short* x_bf   = ws + 25165824;      // [4096][1024]; dead after gemm1
    unsigned short* vt_bf  = x_bf;               // alias: [32][64][2048]

    dim3 blk(256);
    cvt_bf16<<<2048, blk, 0, stream>>>(x,   x_bf,  524288);
    cvt_bf16<<<2048, blk, 0, stream>>>(k_g, kg_bf, 524288);
    transpose_cvt<<<dim3(48, 16), blk, 0, stream>>>(W_qkv, wtq, 1024, 3072);
    transpose_cvt<<<dim3(16, 16), blk, 0, stream>>>(W_out, wto, 1024, 1024);
    gemm_lds<unsigned short><<<dim3(24, 32), blk, 0, stream>>>(
        x_bf, wtq, qkv_ws, 4096, 3072, 1024);
    transpose_v<<<dim3(32, 32), blk, 0, stream>>>(qkv_ws, vt_bf);
    attn4<<<dim3(32, 32), blk, 0, stream>>>(qkv_ws, q_g, kg_bf, vt_bf, y_ws);
    gemm_lds<float><<<dim3(8, 32), blk, 0, stream>>>(
        y_ws, wto, out, 4096, 1024, 1024);
}

// Round 7
// 235.201 us; speedup vs baseline: 1.3863x; 1.3782x over previous
//
#include <hip/hip_runtime.h>
#include <type_traits>

typedef __attribute__((ext_vector_type(8))) short bf16x8;
typedef __attribute__((ext_vector_type(4))) float f32x4;

static __device__ __forceinline__ unsigned short f2bf(float f) {
    unsigned int u = __float_as_uint(f);
    u += 0x7fffu + ((u >> 16) & 1u);
    return (unsigned short)(u >> 16);
}
// round-half-up: 2 VALU ops; P-values only (|rel err| <= 2^-9, tolerance-safe)
static __device__ __forceinline__ unsigned short f2bf_fast(float f) {
    return (unsigned short)((__float_as_uint(f) + 0x8000u) >> 16);
}

static __device__ __forceinline__ float bf2f(short v) {
    return __uint_as_float(((unsigned int)(unsigned short)v) << 16);
}

// f32x8 -> bf16x8, pure vector regs (no stack arrays -> no scratch)
static __device__ __forceinline__ bf16x8 cvt8v(const float* p) {
    f32x4 a = *(const f32x4*)p, b = *(const f32x4*)(p + 4);
    bf16x8 r;
    r[0] = (short)f2bf(a[0]); r[1] = (short)f2bf(a[1]);
    r[2] = (short)f2bf(a[2]); r[3] = (short)f2bf(a[3]);
    r[4] = (short)f2bf(b[0]); r[5] = (short)f2bf(b[1]);
    r[6] = (short)f2bf(b[2]); r[7] = (short)f2bf(b[3]);
    return r;
}
static __device__ __forceinline__ bf16x8 scale8v(bf16x8 v, float s) {
    bf16x8 r;
    #pragma unroll
    for (int j = 0; j < 8; ++j) r[j] = (short)f2bf(bf2f(v[j]) * s);
    return r;
}
static __device__ __forceinline__ uint4 cvt8(const float* p) {
    bf16x8 r = cvt8v(p);
    union { bf16x8 v; uint4 u; } c; c.v = r; return c.u;
}

// async global->LDS, 16B per lane; LDS dest = wave-uniform base + lane*16
static __device__ __forceinline__ void glds16(const unsigned short* g, unsigned short* l) {
    __builtin_amdgcn_global_load_lds(
        (const __attribute__((address_space(1))) unsigned int*)g,
        (__attribute__((address_space(3))) unsigned int*)l, 16, 0, 0);
}

// ---------------------------------------------------------------------------
__global__ __launch_bounds__(256) void cvt_bf16(
    const float* __restrict__ src, unsigned short* __restrict__ dst, int n8)
{
    int i = blockIdx.x * 256 + threadIdx.x;
    if (i < n8) *(uint4*)&dst[(size_t)i * 8] = cvt8(&src[(size_t)i * 8]);
}

// ---------------------------------------------------------------------------
__global__ __launch_bounds__(256) void transpose_cvt(
    const float* __restrict__ src, unsigned short* __restrict__ dst, int R, int C)
{
    __shared__ unsigned short t[64 * 72];
    const int r0 = blockIdx.y * 64, c0 = blockIdx.x * 64;
    const int tid = threadIdx.x;
    #pragma unroll
    for (int i = 0; i < 4; ++i) {
        int idx = tid + i * 256;
        int row = idx >> 4, seg = idx & 15;
        f32x4 v = *(const f32x4*)&src[(size_t)(r0 + row) * C + c0 + seg * 4];
        #pragma unroll
        for (int j = 0; j < 4; ++j) t[row * 72 + seg * 4 + j] = f2bf(v[j]);
    }
    __syncthreads();
    #pragma unroll
    for (int i = 0; i < 2; ++i) {
        int idx = tid + i * 256;
        int row = idx >> 3, seg = idx & 7;
        uint4 tv; unsigned short* tmp = (unsigned short*)&tv;
        #pragma unroll
        for (int j = 0; j < 8; ++j) tmp[j] = t[(seg * 8 + j) * 72 + row];
        *(uint4*)&dst[(size_t)(c0 + row) * R + r0 + seg * 8] = tv;
    }
}

// ---------------------------------------------------------------------------
// V^T precompute: vt[bh][hd=64][L=2048] from qkv_ws V-part (bf16).
// ---------------------------------------------------------------------------
__global__ __launch_bounds__(256) void transpose_v(
    const unsigned short* __restrict__ qkv, unsigned short* __restrict__ vt)
{
    __shared__ unsigned short t[64 * 72];
    const int lt = blockIdx.x, bh = blockIdx.y, b = bh >> 4, h = bh & 15;
    const int tid = threadIdx.x;
    #pragma unroll
    for (int i = 0; i < 2; ++i) {
        int idx = tid + i * 256, row = idx >> 3, seg = idx & 7;
        *(uint4*)&t[row * 72 + seg * 8] =
            *(const uint4*)&qkv[(size_t)(b * 2048 + lt * 64 + row) * 3072 + 2048 + h * 64 + seg * 8];
    }
    __syncthreads();
    #pragma unroll
    for (int i = 0; i < 2; ++i) {
        int idx = tid + i * 256, row = idx >> 3, seg = idx & 7;
        uint4 tv; unsigned short* tmp = (unsigned short*)&tv;
        #pragma unroll
        for (int j = 0; j < 8; ++j) tmp[j] = t[(seg * 8 + j) * 72 + row];
        *(uint4*)&vt[((size_t)bh * 64 + row) * 2048 + lt * 64 + seg * 8] = tv;
    }
}

// ---------------------------------------------------------------------------
// m97-pattern GEMM: C = A[M][K] * Bt[N][K]^T, bf16 in, global_load_lds staging.
// ---------------------------------------------------------------------------
template <typename OT>
__global__ __launch_bounds__(256) void gemm_lds(
    const unsigned short* __restrict__ A, const unsigned short* __restrict__ Bt,
    OT* __restrict__ C, int M, int N, int K)
{
    __shared__ unsigned short As[128 * 32];
    __shared__ unsigned short Bs[128 * 32];
    const int tid = threadIdx.x;
    const int wave = tid >> 6, lane = tid & 63, quad = lane >> 4, l16 = lane & 15;
    const int wr = (wave >> 1) * 64, wc = (wave & 1) * 64;
    const int m0 = blockIdx.y * 128, n0 = blockIdx.x * 128;

    const unsigned short* ga = A  + (size_t)(m0 + wave * 32 + (lane >> 2)) * K + (lane & 3) * 8;
    const unsigned short* gb = Bt + (size_t)(n0 + wave * 32 + (lane >> 2)) * K + (lane & 3) * 8;
    unsigned short* la = &As[wave * 32 * 32];
    unsigned short* lb = &Bs[wave * 32 * 32];
    const size_t step16 = (size_t)16 * K;

    f32x4 acc[4][4];
    #pragma unroll
    for (int i = 0; i < 4; ++i)
        #pragma unroll
        for (int j = 0; j < 4; ++j) acc[i][j] = (f32x4){0.f, 0.f, 0.f, 0.f};

    for (int kt = 0; kt < K; kt += 32) {
        glds16(ga, la);
        glds16(ga + step16, la + 512);
        glds16(gb, lb);
        glds16(gb + step16, lb + 512);
        ga += 32; gb += 32;
        __syncthreads();
        bf16x8 af[4], bf[4];
        #pragma unroll
        for (int i = 0; i < 4; ++i) {
            af[i] = *(const bf16x8*)&As[(wr + i * 16 + l16) * 32 + quad * 8];
            bf[i] = *(const bf16x8*)&Bs[(wc + i * 16 + l16) * 32 + quad * 8];
        }
        #pragma unroll
        for (int mi = 0; mi < 4; ++mi)
            #pragma unroll
            for (int ni = 0; ni < 4; ++ni)
                acc[mi][ni] = __builtin_amdgcn_mfma_f32_16x16x32_bf16(
                    af[mi], bf[ni], acc[mi][ni], 0, 0, 0);
        __syncthreads();
    }
    #pragma unroll
    for (int mi = 0; mi < 4; ++mi)
        #pragma unroll
        for (int ni = 0; ni < 4; ++ni)
            #pragma unroll
            for (int r = 0; r < 4; ++r) {
                int row = m0 + wr + mi * 16 + quad * 4 + r;
                int col = n0 + wc + ni * 16 + l16;
                if constexpr (std::is_same_v<OT, float>)
                    C[(size_t)row * N + col] = acc[mi][ni][r];
                else
                    C[(size_t)row * N + col] = f2bf(acc[mi][ni][r]);
            }
}

// ---------------------------------------------------------------------------
// Dual-score causal flash attention, 64-row q-tiles, 1024 blocks.
// K/G/V staged via async global_load_lds (NO persistent prefetch registers —
// round-6 lesson: those 24 VGPRs spilled ~300 MB of scratch traffic).
// LDS tiles are [64 rows][128 B] with XOR swizzle physChunk = c ^ (row&7),
// applied at both the glds source address and the frag-read address: keeps
// glds's lane-contiguous dest AND makes b128 frag reads 2-way (free).
// Fixed-base softmax (m=0): scores/(ln L*T*sqrt(hd)) are O(1).
// ---------------------------------------------------------------------------
__global__ __launch_bounds__(256, 4) void attn5(
    const unsigned short* __restrict__ qkv, const float* __restrict__ qg,
    const unsigned short* __restrict__ kgb, const unsigned short* __restrict__ vt,
    unsigned short* __restrict__ y)
{
    const int L = 2048, D3 = 3072, Dm = 1024;
    const float SC2 = 0.125f * 1.44269504088896f / 7.6246189861593985f; // log2-domain

    const int qt = 31 - (int)blockIdx.y;   // heavy tiles dispatch first
    const int bh = blockIdx.x, b = bh >> 4, h = bh & 15;
    const int tid = threadIdx.x, wave = tid >> 6, lane = tid & 63;
    const int quad = lane >> 4, l16 = lane & 15;

    __shared__ unsigned short K_l[4096];     // [64][64] swizzled, 8 KB
    __shared__ unsigned short G_l[4096];
    __shared__ unsigned short V_l[4096];     // [hd][key] swizzled
    __shared__ unsigned short P_l[4 * 1152]; // per-wave [16][72] padded
    unsigned short* Pw = &P_l[wave * 1152];

    // Q / Qg fragments pre-scaled by SC2
    bf16x8 qf[2], gf[2];
    {
        const int qrow = qt * 64 + wave * 16 + l16;
        const unsigned short* qp = qkv + (size_t)(b * L + qrow) * D3 + h * 64;
        const float* gp = qg + (size_t)(b * L + qrow) * Dm + h * 64;
        #pragma unroll
        for (int c = 0; c < 2; ++c) {
            qf[c] = scale8v(*(const bf16x8*)(qp + c * 32 + quad * 8), SC2);
            gf[c] = scale8v(cvt8v(gp + c * 32 + quad * 8), SC2);
        }
    }

    f32x4 o[4];
    #pragma unroll
    for (int nd = 0; nd < 4; ++nd) o[nd] = (f32x4){0.f, 0.f, 0.f, 0.f};
    float lsum[4];
    #pragma unroll
    for (int r = 0; r < 4; ++r) lsum[r] = 0.f;

    // staging source: lane covers row r = wave*16 + {0,8} + (lane>>3),
    // physical chunk lane&7, logical chunk c = (lane&7) ^ ((lane>>3)&7)
    const int srow = wave * 16 + (lane >> 3);
    const int c8 = (((lane & 7) ^ (lane >> 3)) & 7) * 8;
    const unsigned short* pk = qkv + (size_t)(b * L + srow) * D3 + 1024 + h * 64 + c8;
    const unsigned short* pg = kgb + (size_t)(b * L + srow) * Dm + h * 64 + c8;
    const unsigned short* pv = vt + ((size_t)bh * 64 + srow) * L + c8;
    unsigned short* lK = &K_l[wave * 1024];
    unsigned short* lG = &G_l[wave * 1024];
    unsigned short* lV = &V_l[wave * 1024];

    // frag-read swizzled byte offsets (per lane)
    const int rb = l16 * 128;
    const int swz0 = ((quad     ^ (l16 & 7)) * 16);
    const int swz1 = (((4 + quad) ^ (l16 & 7)) * 16);

    const int ktmax = qt;
    for (int kt = 0; kt <= ktmax; ++kt) {
        __syncthreads();                       // prev tile's LDS reads done
        glds16(pk, lK); glds16(pk + 8 * D3, lK + 512);
        glds16(pg, lG); glds16(pg + 8 * Dm, lG + 512);
        glds16(pv, lV); glds16(pv + 8 * L,  lV + 512);
        pk += 64 * D3; pg += 64 * Dm; pv += 64;
        __syncthreads();                       // vmcnt drained: tile visible

        // ---- S = (Q K^T + Qg Kg^T), scale pre-folded ----
        f32x4 s[4];
        #pragma unroll
        for (int ni = 0; ni < 4; ++ni) {
            bf16x8 kf0 = *(const bf16x8*)((const char*)K_l + rb + swz0 + ni * 2048);
            bf16x8 kf1 = *(const bf16x8*)((const char*)K_l + rb + swz1 + ni * 2048);
            bf16x8 gb0 = *(const bf16x8*)((const char*)G_l + rb + swz0 + ni * 2048);
            bf16x8 gb1 = *(const bf16x8*)((const char*)G_l + rb + swz1 + ni * 2048);
            f32x4 a = (f32x4){0.f, 0.f, 0.f, 0.f};
            a = __builtin_amdgcn_mfma_f32_16x16x32_bf16(qf[0], kf0, a, 0, 0, 0);
            a = __builtin_amdgcn_mfma_f32_16x16x32_bf16(gf[0], gb0, a, 0, 0, 0);
            a = __builtin_amdgcn_mfma_f32_16x16x32_bf16(qf[1], kf1, a, 0, 0, 0);
            a = __builtin_amdgcn_mfma_f32_16x16x32_bf16(gf[1], gb1, a, 0, 0, 0);
            s[ni] = a;
        }

        // ---- fixed-base exp + causal mask; lane-partial row sums ----
        {
            const int rowbase = qt * 64 + wave * 16 + quad * 4;
            const bool safe = (kt * 64 + 63 <= rowbase);
            #pragma unroll
            for (int ni = 0; ni < 4; ++ni) {
                const int key = kt * 64 + ni * 16 + l16;
                #pragma unroll
                for (int r = 0; r < 4; ++r) {
                    float e = (safe || key <= rowbase + r) ? exp2f(s[ni][r]) : 0.f;
                    lsum[r] += e;
                    Pw[(quad * 4 + r) * 72 + ni * 16 + l16] = f2bf_fast(e);
                }
            }
        }
        asm volatile("s_waitcnt lgkmcnt(0)" ::: "memory");  // P visible to own wave

        // ---- O += P V ----
        bf16x8 pa[2];
        #pragma unroll
        for (int c = 0; c < 2; ++c)
            pa[c] = *(const bf16x8*)&Pw[l16 * 72 + c * 32 + quad * 8];
        #pragma unroll
        for (int nd = 0; nd < 4; ++nd) {
            bf16x8 vf0 = *(const bf16x8*)((const char*)V_l + rb + swz0 + nd * 2048);
            bf16x8 vf1 = *(const bf16x8*)((const char*)V_l + rb + swz1 + nd * 2048);
            o[nd] = __builtin_amdgcn_mfma_f32_16x16x32_bf16(pa[0], vf0, o[nd], 0, 0, 0);
            o[nd] = __builtin_amdgcn_mfma_f32_16x16x32_bf16(pa[1], vf1, o[nd], 0, 0, 0);
        }
    }

    // ---- one-time row-sum reduce + normalize + write ----
    #pragma unroll
    for (int r = 0; r < 4; ++r) {
        float rs = lsum[r];
        #pragma unroll
        for (int off = 1; off < 16; off <<= 1) rs += __shfl_xor(rs, off);
        float inv = 1.f / rs;
        int row = qt * 64 + wave * 16 + quad * 4 + r;
        #pragma unroll
        for (int nd = 0; nd < 4; ++nd)
            y[(size_t)(b * L + row) * Dm + h * 64 + nd * 16 + l16] =
                f2bf(o[nd][r] * inv);
    }
}

// ---------------------------------------------------------------------------
extern "C" void kernel_launch(void* const* d_in, const int* in_sizes, int n_in,
                              void* d_out, int out_size, void* d_ws, size_t ws_size,
                              hipStream_t stream) {
    const float* x     = (const float*)d_in[0];
    const float* q_g   = (const float*)d_in[1];
    const float* k_g   = (const float*)d_in[2];
    const float* W_qkv = (const float*)d_in[3];
    const float* W_out = (const float*)d_in[4];
    float* out = (float*)d_out;
    unsigned short* ws = (unsigned short*)d_ws;

    unsigned short* qkv_ws = ws;                 // [4096][3072]
    unsigned short* y_ws   = ws + 12582912;      // [4096][1024]
    unsigned short* wtq    = ws + 16777216;      // [3072][1024]
    unsigned short* wto    = ws + 19922944;      // [1024][1024]
    unsigned short* kg_bf  = ws + 20971520;      // [4096][1024]
    unsigned short* x_bf   = ws + 25165824;      // [4096][1024]; dead after gemm1
    unsigned short* vt_bf  = x_bf;               // alias: [32][64][2048]

    dim3 blk(256);
    cvt_bf16<<<2048, blk, 0, stream>>>(x,   x_bf,  524288);
    cvt_bf16<<<2048, blk, 0, stream>>>(k_g, kg_bf, 524288);
    transpose_cvt<<<dim3(48, 16), blk, 0, stream>>>(W_qkv, wtq, 1024, 3072);
    transpose_cvt<<<dim3(16, 16), blk, 0, stream>>>(W_out, wto, 1024, 1024);
    gemm_lds<unsigned short><<<dim3(24, 32), blk, 0, stream>>>(
        x_bf, wtq, qkv_ws, 4096, 3072, 1024);
    transpose_v<<<dim3(32, 32), blk, 0, stream>>>(qkv_ws, vt_bf);
    attn5<<<dim3(32, 32), blk, 0, stream>>>(qkv_ws, q_g, kg_bf, vt_bf, y_ws);
    gemm_lds<float><<<dim3(8, 32), blk, 0, stream>>>(
        y_ws, wto, out, 4096, 1024, 1024);
}

// Round 8
// 233.254 us; speedup vs baseline: 1.3978x; 1.0083x over previous
//
#include <hip/hip_runtime.h>
#include <type_traits>

typedef __attribute__((ext_vector_type(8))) short bf16x8;
typedef __attribute__((ext_vector_type(4))) float f32x4;

static __device__ __forceinline__ unsigned short f2bf(float f) {
    unsigned int u = __float_as_uint(f);
    u += 0x7fffu + ((u >> 16) & 1u);
    return (unsigned short)(u >> 16);
}
// round-half-up: 2 VALU ops; P-values only (|rel err| <= 2^-9, tolerance-safe)
static __device__ __forceinline__ unsigned int pack2bf(float lo, float hi) {
    return ((__float_as_uint(lo) + 0x8000u) >> 16) |
           ((__float_as_uint(hi) + 0x8000u) & 0xffff0000u);
}

static __device__ __forceinline__ float bf2f(short v) {
    return __uint_as_float(((unsigned int)(unsigned short)v) << 16);
}

// f32x8 -> bf16x8, pure vector regs (no stack arrays -> no scratch)
static __device__ __forceinline__ bf16x8 cvt8v(const float* p) {
    f32x4 a = *(const f32x4*)p, b = *(const f32x4*)(p + 4);
    bf16x8 r;
    r[0] = (short)f2bf(a[0]); r[1] = (short)f2bf(a[1]);
    r[2] = (short)f2bf(a[2]); r[3] = (short)f2bf(a[3]);
    r[4] = (short)f2bf(b[0]); r[5] = (short)f2bf(b[1]);
    r[6] = (short)f2bf(b[2]); r[7] = (short)f2bf(b[3]);
    return r;
}
static __device__ __forceinline__ bf16x8 scale8v(bf16x8 v, float s) {
    bf16x8 r;
    #pragma unroll
    for (int j = 0; j < 8; ++j) r[j] = (short)f2bf(bf2f(v[j]) * s);
    return r;
}
static __device__ __forceinline__ uint4 cvt8(const float* p) {
    bf16x8 r = cvt8v(p);
    union { bf16x8 v; uint4 u; } c; c.v = r; return c.u;
}

// async global->LDS, 16B per lane; LDS dest = wave-uniform base + lane*16
static __device__ __forceinline__ void glds16(const unsigned short* g, unsigned short* l) {
    __builtin_amdgcn_global_load_lds(
        (const __attribute__((address_space(1))) unsigned int*)g,
        (__attribute__((address_space(3))) unsigned int*)l, 16, 0, 0);
}

// ---------------------------------------------------------------------------
// fused f32->bf16 for x and k_g (one launch, 4096 blocks x 256 x 8 elems)
// ---------------------------------------------------------------------------
__global__ __launch_bounds__(256) void cvt_bf16_2(
    const float* __restrict__ a, unsigned short* __restrict__ da,
    const float* __restrict__ b, unsigned short* __restrict__ db)
{
    int i = blockIdx.x * 256 + threadIdx.x;
    const float* s = (i < 524288) ? a : b;
    unsigned short* d = (i < 524288) ? da : db;
    size_t j = (size_t)((i < 524288) ? i : i - 524288) * 8;
    *(uint4*)&d[j] = cvt8(&s[j]);
}

// ---------------------------------------------------------------------------
__global__ __launch_bounds__(256) void transpose_cvt(
    const float* __restrict__ src, unsigned short* __restrict__ dst, int R, int C)
{
    __shared__ unsigned short t[64 * 72];
    const int r0 = blockIdx.y * 64, c0 = blockIdx.x * 64;
    const int tid = threadIdx.x;
    #pragma unroll
    for (int i = 0; i < 4; ++i) {
        int idx = tid + i * 256;
        int row = idx >> 4, seg = idx & 15;
        f32x4 v = *(const f32x4*)&src[(size_t)(r0 + row) * C + c0 + seg * 4];
        #pragma unroll
        for (int j = 0; j < 4; ++j) t[row * 72 + seg * 4 + j] = f2bf(v[j]);
    }
    __syncthreads();
    #pragma unroll
    for (int i = 0; i < 2; ++i) {
        int idx = tid + i * 256;
        int row = idx >> 3, seg = idx & 7;
        uint4 tv; unsigned short* tmp = (unsigned short*)&tv;
        #pragma unroll
        for (int j = 0; j < 8; ++j) tmp[j] = t[(seg * 8 + j) * 72 + row];
        *(uint4*)&dst[(size_t)(c0 + row) * R + r0 + seg * 8] = tv;
    }
}

// ---------------------------------------------------------------------------
// V^T precompute: vt[bh][hd=64][L=2048] from qkv_ws V-part (bf16).
// ---------------------------------------------------------------------------
__global__ __launch_bounds__(256) void transpose_v(
    const unsigned short* __restrict__ qkv, unsigned short* __restrict__ vt)
{
    __shared__ unsigned short t[64 * 72];
    const int lt = blockIdx.x, bh = blockIdx.y, b = bh >> 4, h = bh & 15;
    const int tid = threadIdx.x;
    #pragma unroll
    for (int i = 0; i < 2; ++i) {
        int idx = tid + i * 256, row = idx >> 3, seg = idx & 7;
        *(uint4*)&t[row * 72 + seg * 8] =
            *(const uint4*)&qkv[(size_t)(b * 2048 + lt * 64 + row) * 3072 + 2048 + h * 64 + seg * 8];
    }
    __syncthreads();
    #pragma unroll
    for (int i = 0; i < 2; ++i) {
        int idx = tid + i * 256, row = idx >> 3, seg = idx & 7;
        uint4 tv; unsigned short* tmp = (unsigned short*)&tv;
        #pragma unroll
        for (int j = 0; j < 8; ++j) tmp[j] = t[(seg * 8 + j) * 72 + row];
        *(uint4*)&vt[((size_t)bh * 64 + row) * 2048 + lt * 64 + seg * 8] = tv;
    }
}

// ---------------------------------------------------------------------------
// m97-pattern GEMM: C = A[M][K] * Bt[N][K]^T, bf16 in, global_load_lds staging.
// ---------------------------------------------------------------------------
template <typename OT>
__global__ __launch_bounds__(256) void gemm_lds(
    const unsigned short* __restrict__ A, const unsigned short* __restrict__ Bt,
    OT* __restrict__ C, int M, int N, int K)
{
    __shared__ unsigned short As[128 * 32];
    __shared__ unsigned short Bs[128 * 32];
    const int tid = threadIdx.x;
    const int wave = tid >> 6, lane = tid & 63, quad = lane >> 4, l16 = lane & 15;
    const int wr = (wave >> 1) * 64, wc = (wave & 1) * 64;
    const int m0 = blockIdx.y * 128, n0 = blockIdx.x * 128;

    const unsigned short* ga = A  + (size_t)(m0 + wave * 32 + (lane >> 2)) * K + (lane & 3) * 8;
    const unsigned short* gb = Bt + (size_t)(n0 + wave * 32 + (lane >> 2)) * K + (lane & 3) * 8;
    unsigned short* la = &As[wave * 32 * 32];
    unsigned short* lb = &Bs[wave * 32 * 32];
    const size_t step16 = (size_t)16 * K;

    f32x4 acc[4][4];
    #pragma unroll
    for (int i = 0; i < 4; ++i)
        #pragma unroll
        for (int j = 0; j < 4; ++j) acc[i][j] = (f32x4){0.f, 0.f, 0.f, 0.f};

    for (int kt = 0; kt < K; kt += 32) {
        glds16(ga, la);
        glds16(ga + step16, la + 512);
        glds16(gb, lb);
        glds16(gb + step16, lb + 512);
        ga += 32; gb += 32;
        __syncthreads();
        bf16x8 af[4], bf[4];
        #pragma unroll
        for (int i = 0; i < 4; ++i) {
            af[i] = *(const bf16x8*)&As[(wr + i * 16 + l16) * 32 + quad * 8];
            bf[i] = *(const bf16x8*)&Bs[(wc + i * 16 + l16) * 32 + quad * 8];
        }
        #pragma unroll
        for (int mi = 0; mi < 4; ++mi)
            #pragma unroll
            for (int ni = 0; ni < 4; ++ni)
                acc[mi][ni] = __builtin_amdgcn_mfma_f32_16x16x32_bf16(
                    af[mi], bf[ni], acc[mi][ni], 0, 0, 0);
        __syncthreads();
    }
    #pragma unroll
    for (int mi = 0; mi < 4; ++mi)
        #pragma unroll
        for (int ni = 0; ni < 4; ++ni)
            #pragma unroll
            for (int r = 0; r < 4; ++r) {
                int row = m0 + wr + mi * 16 + quad * 4 + r;
                int col = n0 + wc + ni * 16 + l16;
                if constexpr (std::is_same_v<OT, float>)
                    C[(size_t)row * N + col] = acc[mi][ni][r];
                else
                    C[(size_t)row * N + col] = f2bf(acc[mi][ni][r]);
            }
}

// ---------------------------------------------------------------------------
// Dual-score causal flash attention, 64-row q-tiles, 1024 blocks, glds staging.
// Round-8 changes vs attn5:
//  * S computed TRANSPOSED (mfma A=K, B=Q; identical lane layouts, same LDS
//    reads): lane holds 4 consecutive keys for one q-row -> P-writes are
//    4x ds_write_b64 (was 16x ds_write_b16), lsum is a single scalar/lane.
//  * Causal mask hoisted: kt<qt tiles are provably unmasked (kt*64+63 <
//    qt*64 <= rowbase); only the kt==qt tile runs the masked path, and with
//    S^T only the ni==wave chunk needs per-lane compares.
// Fixed-base softmax (m=0): scores/(ln L*T*sqrt(hd)) are O(1).
// ---------------------------------------------------------------------------
__global__ __launch_bounds__(256, 4) void attn6(
    const unsigned short* __restrict__ qkv, const float* __restrict__ qg,
    const unsigned short* __restrict__ kgb, const unsigned short* __restrict__ vt,
    unsigned short* __restrict__ y)
{
    const int L = 2048, D3 = 3072, Dm = 1024;
    const float SC2 = 0.125f * 1.44269504088896f / 7.6246189861593985f; // log2-domain

    const int qt = 31 - (int)blockIdx.y;   // heavy tiles dispatch first
    const int bh = blockIdx.x, b = bh >> 4, h = bh & 15;
    const int tid = threadIdx.x, wave = tid >> 6, lane = tid & 63;
    const int quad = lane >> 4, l16 = lane & 15;

    __shared__ unsigned short K_l[4096];     // [64][64] swizzled, 8 KB
    __shared__ unsigned short G_l[4096];
    __shared__ unsigned short V_l[4096];     // [hd][key] swizzled
    __shared__ unsigned short P_l[4 * 1152]; // per-wave [16 qrows][72]
    unsigned short* Pw = &P_l[wave * 1152];

    // Q / Qg fragments pre-scaled by SC2 (used as MFMA B-operand: same layout)
    bf16x8 qf[2], gf[2];
    {
        const int qrow = qt * 64 + wave * 16 + l16;
        const unsigned short* qp = qkv + (size_t)(b * L + qrow) * D3 + h * 64;
        const float* gp = qg + (size_t)(b * L + qrow) * Dm + h * 64;
        #pragma unroll
        for (int c = 0; c < 2; ++c) {
            qf[c] = scale8v(*(const bf16x8*)(qp + c * 32 + quad * 8), SC2);
            gf[c] = scale8v(cvt8v(gp + c * 32 + quad * 8), SC2);
        }
    }

    f32x4 o[4];
    #pragma unroll
    for (int nd = 0; nd < 4; ++nd) o[nd] = (f32x4){0.f, 0.f, 0.f, 0.f};
    float lsum = 0.f;   // partial row-sum for qrow = l16 (keys ni*16+quad*4+r)

    // staging source: lane covers row r = wave*16 + {0,8} + (lane>>3),
    // physical chunk lane&7, logical chunk c = (lane&7) ^ ((lane>>3)&7)
    const int srow = wave * 16 + (lane >> 3);
    const int c8 = (((lane & 7) ^ (lane >> 3)) & 7) * 8;
    const unsigned short* pk = qkv + (size_t)(b * L + srow) * D3 + 1024 + h * 64 + c8;
    const unsigned short* pg = kgb + (size_t)(b * L + srow) * Dm + h * 64 + c8;
    const unsigned short* pv = vt + ((size_t)bh * 64 + srow) * L + c8;
    unsigned short* lK = &K_l[wave * 1024];
    unsigned short* lG = &G_l[wave * 1024];
    unsigned short* lV = &V_l[wave * 1024];

    // frag-read swizzled byte offsets (per lane)
    const int rb = l16 * 128;
    const int swz0 = ((quad     ^ (l16 & 7)) * 16);
    const int swz1 = (((4 + quad) ^ (l16 & 7)) * 16);

    // ---- main loop: kt in [0, qt) -- provably unmasked ----
    for (int kt = 0; kt < qt; ++kt) {
        __syncthreads();
        glds16(pk, lK); glds16(pk + 8 * D3, lK + 512);
        glds16(pg, lG); glds16(pg + 8 * Dm, lG + 512);
        glds16(pv, lV); glds16(pv + 8 * L,  lV + 512);
        pk += 64 * D3; pg += 64 * Dm; pv += 64;
        __syncthreads();

        // S^T: A = K/G frags (m=key), B = Q/Qg frags (n=qrow)
        #pragma unroll
        for (int ni = 0; ni < 4; ++ni) {
            bf16x8 kf0 = *(const bf16x8*)((const char*)K_l + rb + swz0 + ni * 2048);
            bf16x8 kf1 = *(const bf16x8*)((const char*)K_l + rb + swz1 + ni * 2048);
            bf16x8 gb0 = *(const bf16x8*)((const char*)G_l + rb + swz0 + ni * 2048);
            bf16x8 gb1 = *(const bf16x8*)((const char*)G_l + rb + swz1 + ni * 2048);
            f32x4 a = (f32x4){0.f, 0.f, 0.f, 0.f};
            a = __builtin_amdgcn_mfma_f32_16x16x32_bf16(kf0, qf[0], a, 0, 0, 0);
            a = __builtin_amdgcn_mfma_f32_16x16x32_bf16(gb0, gf[0], a, 0, 0, 0);
            a = __builtin_amdgcn_mfma_f32_16x16x32_bf16(kf1, qf[1], a, 0, 0, 0);
            a = __builtin_amdgcn_mfma_f32_16x16x32_bf16(gb1, gf[1], a, 0, 0, 0);
            // s[key = kt*64 + ni*16 + quad*4 + r][qrow = l16]
            float e0 = exp2f(a[0]), e1 = exp2f(a[1]);
            float e2 = exp2f(a[2]), e3 = exp2f(a[3]);
            lsum += (e0 + e1) + (e2 + e3);
            unsigned int p01 = pack2bf(e0, e1), p23 = pack2bf(e2, e3);
            *(unsigned long long*)&Pw[l16 * 72 + ni * 16 + quad * 4] =
                ((unsigned long long)p23 << 32) | p01;
        }
        asm volatile("s_waitcnt lgkmcnt(0)" ::: "memory");  // P visible to own wave

        // O += P V   (A = P[m=qrow][k=key], B = V^T rows -> D[qrow][hd])
        bf16x8 pa[2];
        #pragma unroll
        for (int c = 0; c < 2; ++c)
            pa[c] = *(const bf16x8*)&Pw[l16 * 72 + c * 32 + quad * 8];
        #pragma unroll
        for (int nd = 0; nd < 4; ++nd) {
            bf16x8 vf0 = *(const bf16x8*)((const char*)V_l + rb + swz0 + nd * 2048);
            bf16x8 vf1 = *(const bf16x8*)((const char*)V_l + rb + swz1 + nd * 2048);
            o[nd] = __builtin_amdgcn_mfma_f32_16x16x32_bf16(pa[0], vf0, o[nd], 0, 0, 0);
            o[nd] = __builtin_amdgcn_mfma_f32_16x16x32_bf16(pa[1], vf1, o[nd], 0, 0, 0);
        }
    }

    // ---- diagonal tile kt == qt: 3-case mask (ni vs wave), wave-uniform ----
    {
        __syncthreads();
        glds16(pk, lK); glds16(pk + 8 * D3, lK + 512);
        glds16(pg, lG); glds16(pg + 8 * Dm, lG + 512);
        glds16(pv, lV); glds16(pv + 8 * L,  lV + 512);
        __syncthreads();

        #pragma unroll
        for (int ni = 0; ni < 4; ++ni) {
            if (ni > wave) {   // fully masked: zero P
                *(unsigned long long*)&Pw[l16 * 72 + ni * 16 + quad * 4] = 0ull;
                continue;
            }
            bf16x8 kf0 = *(const bf16x8*)((const char*)K_l + rb + swz0 + ni * 2048);
            bf16x8 kf1 = *(const bf16x8*)((const char*)K_l + rb + swz1 + ni * 2048);
            bf16x8 gb0 = *(const bf16x8*)((const char*)G_l + rb + swz0 + ni * 2048);
            bf16x8 gb1 = *(const bf16x8*)((const char*)G_l + rb + swz1 + ni * 2048);
            f32x4 a = (f32x4){0.f, 0.f, 0.f, 0.f};
            a = __builtin_amdgcn_mfma_f32_16x16x32_bf16(kf0, qf[0], a, 0, 0, 0);
            a = __builtin_amdgcn_mfma_f32_16x16x32_bf16(gb0, gf[0], a, 0, 0, 0);
            a = __builtin_amdgcn_mfma_f32_16x16x32_bf16(kf1, qf[1], a, 0, 0, 0);
            a = __builtin_amdgcn_mfma_f32_16x16x32_bf16(gb1, gf[1], a, 0, 0, 0);
            float e0, e1, e2, e3;
            if (ni < wave) {   // fully unmasked
                e0 = exp2f(a[0]); e1 = exp2f(a[1]);
                e2 = exp2f(a[2]); e3 = exp2f(a[3]);
            } else {           // ni == wave: keep key_off quad*4+r <= l16
                e0 = (quad * 4 + 0 <= l16) ? exp2f(a[0]) : 0.f;
                e1 = (quad * 4 + 1 <= l16) ? exp2f(a[1]) : 0.f;
                e2 = (quad * 4 + 2 <= l16) ? exp2f(a[2]) : 0.f;
                e3 = (quad * 4 + 3 <= l16) ? exp2f(a[3]) : 0.f;
            }
            lsum += (e0 + e1) + (e2 + e3);
            unsigned int p01 = pack2bf(e0, e1), p23 = pack2bf(e2, e3);
            *(unsigned long long*)&Pw[l16 * 72 + ni * 16 + quad * 4] =
                ((unsigned long long)p23 << 32) | p01;
        }
        asm volatile("s_waitcnt lgkmcnt(0)" ::: "memory");

        bf16x8 pa[2];
        #pragma unroll
        for (int c = 0; c < 2; ++c)
            pa[c] = *(const bf16x8*)&Pw[l16 * 72 + c * 32 + quad * 8];
        #pragma unroll
        for (int nd = 0; nd < 4; ++nd) {
            bf16x8 vf0 = *(const bf16x8*)((const char*)V_l + rb + swz0 + nd * 2048);
            bf16x8 vf1 = *(const bf16x8*)((const char*)V_l + rb + swz1 + nd * 2048);
            o[nd] = __builtin_amdgcn_mfma_f32_16x16x32_bf16(pa[0], vf0, o[nd], 0, 0, 0);
            o[nd] = __builtin_amdgcn_mfma_f32_16x16x32_bf16(pa[1], vf1, o[nd], 0, 0, 0);
        }
    }

    // ---- reduce lsum across quads (same l16), fetch per-row inv, write ----
    float rs = lsum;
    rs += __shfl_xor(rs, 16);
    rs += __shfl_xor(rs, 32);          // every lane: full sum for qrow = l16
    #pragma unroll
    for (int r = 0; r < 4; ++r) {
        float inv = 1.f / __shfl(rs, (lane & 48) | (quad * 4 + r));
        int row = qt * 64 + wave * 16 + quad * 4 + r;
        #pragma unroll
        for (int nd = 0; nd < 4; ++nd)
            y[(size_t)(b * L + row) * Dm + h * 64 + nd * 16 + l16] =
                f2bf(o[nd][r] * inv);
    }
}

// ---------------------------------------------------------------------------
extern "C" void kernel_launch(void* const* d_in, const int* in_sizes, int n_in,
                              void* d_out, int out_size, void* d_ws, size_t ws_size,
                              hipStream_t stream) {
    const float* x     = (const float*)d_in[0];
    const float* q_g   = (const float*)d_in[1];
    const float* k_g   = (const float*)d_in[2];
    const float* W_qkv = (const float*)d_in[3];
    const float* W_out = (const float*)d_in[4];
    float* out = (float*)d_out;
    unsigned short* ws = (unsigned short*)d_ws;

    unsigned short* qkv_ws = ws;                 // [4096][3072]
    unsigned short* y_ws   = ws + 12582912;      // [4096][1024]
    unsigned short* wtq    = ws + 16777216;      // [3072][1024]
    unsigned short* wto    = ws + 19922944;      // [1024][1024]
    unsigned short* kg_bf  = ws + 20971520;      // [4096][1024]
    unsigned short* x_bf   = ws + 25165824;      // [4096][1024]; dead after gemm1
    unsigned short* vt_bf  = x_bf;               // alias: [32][64][2048]

    dim3 blk(256);
    cvt_bf16_2<<<4096, blk, 0, stream>>>(x, x_bf, k_g, kg_bf);
    transpose_cvt<<<dim3(48, 16), blk, 0, stream>>>(W_qkv, wtq, 1024, 3072);
    transpose_cvt<<<dim3(16, 16), blk, 0, stream>>>(W_out, wto, 1024, 1024);
    gemm_lds<unsigned short><<<dim3(24, 32), blk, 0, stream>>>(
        x_bf, wtq, qkv_ws, 4096, 3072, 1024);
    transpose_v<<<dim3(32, 32), blk, 0, stream>>>(qkv_ws, vt_bf);
    attn6<<<dim3(32, 32), blk, 0, stream>>>(qkv_ws, q_g, kg_bf, vt_bf, y_ws);
    gemm_lds<float><<<dim3(8, 32), blk, 0, stream>>>(
        y_ws, wto, out, 4096, 1024, 1024);
}

// Round 9
// 225.569 us; speedup vs baseline: 1.4454x; 1.0341x over previous
//
#include <hip/hip_runtime.h>

typedef __attribute__((ext_vector_type(8))) short bf16x8;
typedef __attribute__((ext_vector_type(4))) float f32x4;

static __device__ __forceinline__ unsigned short f2bf(float f) {
    unsigned int u = __float_as_uint(f);
    u += 0x7fffu + ((u >> 16) & 1u);
    return (unsigned short)(u >> 16);
}
// round-half-up: P-values only (|rel err| <= 2^-9, tolerance-safe)
static __device__ __forceinline__ unsigned int pack2bf(float lo, float hi) {
    return ((__float_as_uint(lo) + 0x8000u) >> 16) |
           ((__float_as_uint(hi) + 0x8000u) & 0xffff0000u);
}
static __device__ __forceinline__ float bf2f(short v) {
    return __uint_as_float(((unsigned int)(unsigned short)v) << 16);
}
static __device__ __forceinline__ bf16x8 cvt8v(const float* p) {
    f32x4 a = *(const f32x4*)p, b = *(const f32x4*)(p + 4);
    bf16x8 r;
    r[0] = (short)f2bf(a[0]); r[1] = (short)f2bf(a[1]);
    r[2] = (short)f2bf(a[2]); r[3] = (short)f2bf(a[3]);
    r[4] = (short)f2bf(b[0]); r[5] = (short)f2bf(b[1]);
    r[6] = (short)f2bf(b[2]); r[7] = (short)f2bf(b[3]);
    return r;
}
static __device__ __forceinline__ bf16x8 scale8v(bf16x8 v, float s) {
    bf16x8 r;
    #pragma unroll
    for (int j = 0; j < 8; ++j) r[j] = (short)f2bf(bf2f(v[j]) * s);
    return r;
}
static __device__ __forceinline__ uint4 cvt8(const float* p) {
    bf16x8 r = cvt8v(p);
    union { bf16x8 v; uint4 u; } c; c.v = r; return c.u;
}
// async global->LDS, 16B/lane; LDS dest = wave-uniform base + lane*16
static __device__ __forceinline__ void glds16(const unsigned short* g, unsigned short* l) {
    __builtin_amdgcn_global_load_lds(
        (const __attribute__((address_space(1))) unsigned int*)g,
        (__attribute__((address_space(3))) unsigned int*)l, 16, 0, 0);
}

// ---------------------------------------------------------------------------
// Fused prep: cvt x -> x_bf, cvt k_g -> kg_bf, transpose+cvt W_qkv, W_out.
// grid 5120: [0,2048) x | [2048,4096) k_g | [4096,4864) Wqkv | [4864,5120) Wout
// ---------------------------------------------------------------------------
static __device__ __forceinline__ void transpose_tile(
    const float* __restrict__ src, unsigned short* __restrict__ dst,
    int R, int C, int bx, int by, int tid)
{
    __shared__ unsigned short t[64 * 72];
    const int r0 = by * 64, c0 = bx * 64;
    #pragma unroll
    for (int i = 0; i < 4; ++i) {
        int idx = tid + i * 256;
        int row = idx >> 4, seg = idx & 15;
        f32x4 v = *(const f32x4*)&src[(size_t)(r0 + row) * C + c0 + seg * 4];
        #pragma unroll
        for (int j = 0; j < 4; ++j) t[row * 72 + seg * 4 + j] = f2bf(v[j]);
    }
    __syncthreads();
    #pragma unroll
    for (int i = 0; i < 2; ++i) {
        int idx = tid + i * 256;
        int row = idx >> 3, seg = idx & 7;
        uint4 tv; unsigned short* tmp = (unsigned short*)&tv;
        #pragma unroll
        for (int j = 0; j < 8; ++j) tmp[j] = t[(seg * 8 + j) * 72 + row];
        *(uint4*)&dst[(size_t)(c0 + row) * R + r0 + seg * 8] = tv;
    }
}

__global__ __launch_bounds__(256) void prep_all(
    const float* __restrict__ x, unsigned short* __restrict__ x_bf,
    const float* __restrict__ kg, unsigned short* __restrict__ kg_bf,
    const float* __restrict__ Wq, unsigned short* __restrict__ wtq,
    const float* __restrict__ Wo, unsigned short* __restrict__ wto)
{
    const int t = blockIdx.x, tid = threadIdx.x;
    if (t < 2048) {
        size_t j = ((size_t)t * 256 + tid) * 8;
        *(uint4*)&x_bf[j] = cvt8(&x[j]);
    } else if (t < 4096) {
        size_t j = ((size_t)(t - 2048) * 256 + tid) * 8;
        *(uint4*)&kg_bf[j] = cvt8(&kg[j]);
    } else if (t < 4864) {
        int tt = t - 4096;               // W_qkv [1024][3072]: 48 col-tiles x 16
        transpose_tile(Wq, wtq, 1024, 3072, tt % 48, tt / 48, tid);
    } else {
        int tt = t - 4864;               // W_out [1024][1024]
        transpose_tile(Wo, wto, 1024, 1024, tt & 15, tt >> 4, tid);
    }
}

// ---------------------------------------------------------------------------
// gemm_qkv: qkv = x_bf @ wtq^T.  Q,K cols (bx<16) -> qk[4096][2048].
// V cols (bx>=16) -> written TRANSPOSED to vt[bh][hd=64][L=2048] via LDS.
// 128x128 tile, BK=32, glds16 staging (m97 pattern).
// ---------------------------------------------------------------------------
__global__ __launch_bounds__(256) void gemm_qkv(
    const unsigned short* __restrict__ A, const unsigned short* __restrict__ Bt,
    unsigned short* __restrict__ qk, unsigned short* __restrict__ vt)
{
    const int K = 1024;
    __shared__ unsigned short As[128 * 32];
    __shared__ unsigned short Bs[128 * 32];
    __shared__ unsigned short Tb[128 * 136];   // V-transpose scratch
    const int tid = threadIdx.x;
    const int wave = tid >> 6, lane = tid & 63, quad = lane >> 4, l16 = lane & 15;
    const int wr = (wave >> 1) * 64, wc = (wave & 1) * 64;
    const int m0 = blockIdx.y * 128, n0 = blockIdx.x * 128;

    const unsigned short* ga = A  + (size_t)(m0 + wave * 32 + (lane >> 2)) * K + (lane & 3) * 8;
    const unsigned short* gb = Bt + (size_t)(n0 + wave * 32 + (lane >> 2)) * K + (lane & 3) * 8;
    unsigned short* la = &As[wave * 32 * 32];
    unsigned short* lb = &Bs[wave * 32 * 32];
    const size_t step16 = (size_t)16 * K;

    f32x4 acc[4][4];
    #pragma unroll
    for (int i = 0; i < 4; ++i)
        #pragma unroll
        for (int j = 0; j < 4; ++j) acc[i][j] = (f32x4){0.f, 0.f, 0.f, 0.f};

    for (int kt = 0; kt < K; kt += 32) {
        glds16(ga, la); glds16(ga + step16, la + 512);
        glds16(gb, lb); glds16(gb + step16, lb + 512);
        ga += 32; gb += 32;
        __syncthreads();
        bf16x8 af[4], bf[4];
        #pragma unroll
        for (int i = 0; i < 4; ++i) {
            af[i] = *(const bf16x8*)&As[(wr + i * 16 + l16) * 32 + quad * 8];
            bf[i] = *(const bf16x8*)&Bs[(wc + i * 16 + l16) * 32 + quad * 8];
        }
        #pragma unroll
        for (int mi = 0; mi < 4; ++mi)
            #pragma unroll
            for (int ni = 0; ni < 4; ++ni)
                acc[mi][ni] = __builtin_amdgcn_mfma_f32_16x16x32_bf16(
                    af[mi], bf[ni], acc[mi][ni], 0, 0, 0);
        __syncthreads();
    }

    if (blockIdx.x < 16) {        // Q|K part: normal write, stride 2048
        #pragma unroll
        for (int mi = 0; mi < 4; ++mi)
            #pragma unroll
            for (int ni = 0; ni < 4; ++ni)
                #pragma unroll
                for (int r = 0; r < 4; ++r) {
                    int row = m0 + wr + mi * 16 + quad * 4 + r;
                    int col = n0 + wc + ni * 16 + l16;
                    qk[(size_t)row * 2048 + col] = f2bf(acc[mi][ni][r]);
                }
    } else {                      // V part: transpose via LDS -> vt[bh][hd][L]
        __syncthreads();
        #pragma unroll
        for (int mi = 0; mi < 4; ++mi)
            #pragma unroll
            for (int ni = 0; ni < 4; ++ni)
                #pragma unroll
                for (int r = 0; r < 4; ++r) {
                    int col = wc + ni * 16 + l16;            // hd-ish (0..127)
                    int row = wr + mi * 16 + quad * 4 + r;   // pos (0..127)
                    Tb[col * 136 + row] = f2bf(acc[mi][ni][r]);
                }
        __syncthreads();
        const int col = tid >> 1, r0 = (tid & 1) * 64;
        const int bh = (m0 >> 11) * 16 + ((int)blockIdx.x - 16) * 2 + (col >> 6);
        size_t base = ((size_t)bh * 64 + (col & 63)) * 2048 + (m0 & 2047) + r0;
        #pragma unroll
        for (int k = 0; k < 8; ++k)
            *(uint4*)&vt[base + k * 8] = *(const uint4*)&Tb[col * 136 + r0 + k * 8];
    }
}

// ---------------------------------------------------------------------------
// gemm2: out = y_ws @ wto^T, f32 out.  128(M) x 64(N) tile -> 512 blocks, 2/CU.
// 4 waves: 2x2, each 64x32.
// ---------------------------------------------------------------------------
__global__ __launch_bounds__(256) void gemm_n64(
    const unsigned short* __restrict__ A, const unsigned short* __restrict__ Bt,
    float* __restrict__ C)
{
    const int K = 1024, N = 1024;
    __shared__ unsigned short As[128 * 32];
    __shared__ unsigned short Bs[64 * 32];
    const int tid = threadIdx.x;
    const int wave = tid >> 6, lane = tid & 63, quad = lane >> 4, l16 = lane & 15;
    const int wr = (wave >> 1) * 64, wc = (wave & 1) * 32;
    const int m0 = blockIdx.y * 128, n0 = blockIdx.x * 64;

    const unsigned short* ga = A  + (size_t)(m0 + wave * 32 + (lane >> 2)) * K + (lane & 3) * 8;
    const unsigned short* gb = Bt + (size_t)(n0 + wave * 16 + (lane >> 2)) * K + (lane & 3) * 8;
    unsigned short* la = &As[wave * 32 * 32];
    unsigned short* lb = &Bs[wave * 16 * 32];
    const size_t step16 = (size_t)16 * K;

    f32x4 acc[4][2];
    #pragma unroll
    for (int i = 0; i < 4; ++i)
        #pragma unroll
        for (int j = 0; j < 2; ++j) acc[i][j] = (f32x4){0.f, 0.f, 0.f, 0.f};

    for (int kt = 0; kt < K; kt += 32) {
        glds16(ga, la); glds16(ga + step16, la + 512);
        glds16(gb, lb);
        ga += 32; gb += 32;
        __syncthreads();
        bf16x8 af[4], bf[2];
        #pragma unroll
        for (int i = 0; i < 4; ++i)
            af[i] = *(const bf16x8*)&As[(wr + i * 16 + l16) * 32 + quad * 8];
        #pragma unroll
        for (int i = 0; i < 2; ++i)
            bf[i] = *(const bf16x8*)&Bs[(wc + i * 16 + l16) * 32 + quad * 8];
        #pragma unroll
        for (int mi = 0; mi < 4; ++mi)
            #pragma unroll
            for (int ni = 0; ni < 2; ++ni)
                acc[mi][ni] = __builtin_amdgcn_mfma_f32_16x16x32_bf16(
                    af[mi], bf[ni], acc[mi][ni], 0, 0, 0);
        __syncthreads();
    }
    #pragma unroll
    for (int mi = 0; mi < 4; ++mi)
        #pragma unroll
        for (int ni = 0; ni < 2; ++ni)
            #pragma unroll
            for (int r = 0; r < 4; ++r) {
                int row = m0 + wr + mi * 16 + quad * 4 + r;
                int col = n0 + wc + ni * 16 + l16;
                C[(size_t)row * N + col] = acc[mi][ni][r];
            }
}

// ---------------------------------------------------------------------------
// Dual-score causal flash attention, 64-row q-tiles, 1024 blocks.
// Round-9: P buffer = [16][64]/wave with XOR chunk-swizzle (write chunk
// (ni*2+(quad>>1))^(l16&7), read (c*4+quad)^(l16&7)) -> LDS exactly 32768 B
// -> 5 blocks/CU, and conflict-free P access.
// S computed transposed; mask hoisted to diagonal tile; fixed-base softmax.
// ---------------------------------------------------------------------------
__global__ __launch_bounds__(256, 5) void attn7(
    const unsigned short* __restrict__ qk, const float* __restrict__ qg,
    const unsigned short* __restrict__ kgb, const unsigned short* __restrict__ vt,
    unsigned short* __restrict__ y)
{
    const int L = 2048, DS = 2048, Dm = 1024;
    const float SC2 = 0.125f * 1.44269504088896f / 7.6246189861593985f;

    const int qt = 31 - (int)blockIdx.y;   // heavy tiles dispatch first
    const int bh = blockIdx.x, b = bh >> 4, h = bh & 15;
    const int tid = threadIdx.x, wave = tid >> 6, lane = tid & 63;
    const int quad = lane >> 4, l16 = lane & 15;

    __shared__ unsigned short K_l[4096];     // [64][64] swizzled
    __shared__ unsigned short G_l[4096];
    __shared__ unsigned short V_l[4096];     // [hd][key] swizzled
    __shared__ unsigned short P_l[4096];     // per-wave [16][64] swizzled
    unsigned short* Pw = &P_l[wave * 1024];

    bf16x8 qf[2], gf[2];
    {
        const int qrow = qt * 64 + wave * 16 + l16;
        const unsigned short* qp = qk + (size_t)(b * L + qrow) * DS + h * 64;
        const float* gp = qg + (size_t)(b * L + qrow) * Dm + h * 64;
        #pragma unroll
        for (int c = 0; c < 2; ++c) {
            qf[c] = scale8v(*(const bf16x8*)(qp + c * 32 + quad * 8), SC2);
            gf[c] = scale8v(cvt8v(gp + c * 32 + quad * 8), SC2);
        }
    }

    f32x4 o[4];
    #pragma unroll
    for (int nd = 0; nd < 4; ++nd) o[nd] = (f32x4){0.f, 0.f, 0.f, 0.f};
    float lsum = 0.f;

    const int srow = wave * 16 + (lane >> 3);
    const int c8 = (((lane & 7) ^ (lane >> 3)) & 7) * 8;
    const unsigned short* pk = qk + (size_t)(b * L + srow) * DS + 1024 + h * 64 + c8;
    const unsigned short* pg = kgb + (size_t)(b * L + srow) * Dm + h * 64 + c8;
    const unsigned short* pv = vt + ((size_t)bh * 64 + srow) * L + c8;
    unsigned short* lK = &K_l[wave * 1024];
    unsigned short* lG = &G_l[wave * 1024];
    unsigned short* lV = &V_l[wave * 1024];

    const int rb = l16 * 128;
    const int swz0 = ((quad     ^ (l16 & 7)) * 16);
    const int swz1 = (((4 + quad) ^ (l16 & 7)) * 16);
    // P write: short idx l16*64 + ((ni*2+(quad>>1))^(l16&7))*8 + (quad&1)*4
    const int pwb = l16 * 64 + (quad & 1) * 4;
    const int pwc = quad >> 1, pxr = l16 & 7;

    for (int kt = 0; kt < qt; ++kt) {
        __syncthreads();
        glds16(pk, lK); glds16(pk + 8 * DS, lK + 512);
        glds16(pg, lG); glds16(pg + 8 * Dm, lG + 512);
        glds16(pv, lV); glds16(pv + 8 * L,  lV + 512);
        pk += 64 * DS; pg += 64 * Dm; pv += 64;
        __syncthreads();

        #pragma unroll
        for (int ni = 0; ni < 4; ++ni) {
            bf16x8 kf0 = *(const bf16x8*)((const char*)K_l + rb + swz0 + ni * 2048);
            bf16x8 kf1 = *(const bf16x8*)((const char*)K_l + rb + swz1 + ni * 2048);
            bf16x8 gb0 = *(const bf16x8*)((const char*)G_l + rb + swz0 + ni * 2048);
            bf16x8 gb1 = *(const bf16x8*)((const char*)G_l + rb + swz1 + ni * 2048);
            f32x4 a = (f32x4){0.f, 0.f, 0.f, 0.f};
            a = __builtin_amdgcn_mfma_f32_16x16x32_bf16(kf0, qf[0], a, 0, 0, 0);
            a = __builtin_amdgcn_mfma_f32_16x16x32_bf16(gb0, gf[0], a, 0, 0, 0);
            a = __builtin_amdgcn_mfma_f32_16x16x32_bf16(kf1, qf[1], a, 0, 0, 0);
            a = __builtin_amdgcn_mfma_f32_16x16x32_bf16(gb1, gf[1], a, 0, 0, 0);
            float e0 = exp2f(a[0]), e1 = exp2f(a[1]);
            float e2 = exp2f(a[2]), e3 = exp2f(a[3]);
            lsum += (e0 + e1) + (e2 + e3);
            unsigned int p01 = pack2bf(e0, e1), p23 = pack2bf(e2, e3);
            *(unsigned long long*)&Pw[pwb + (((ni * 2 + pwc) ^ pxr) * 8)] =
                ((unsigned long long)p23 << 32) | p01;
        }
        asm volatile("s_waitcnt lgkmcnt(0)" ::: "memory");

        bf16x8 pa[2];
        #pragma unroll
        for (int c = 0; c < 2; ++c)
            pa[c] = *(const bf16x8*)&Pw[l16 * 64 + (((c * 4 + quad) ^ pxr) * 8)];
        #pragma unroll
        for (int nd = 0; nd < 4; ++nd) {
            bf16x8 vf0 = *(const bf16x8*)((const char*)V_l + rb + swz0 + nd * 2048);
            bf16x8 vf1 = *(const bf16x8*)((const char*)V_l + rb + swz1 + nd * 2048);
            o[nd] = __builtin_amdgcn_mfma_f32_16x16x32_bf16(pa[0], vf0, o[nd], 0, 0, 0);
            o[nd] = __builtin_amdgcn_mfma_f32_16x16x32_bf16(pa[1], vf1, o[nd], 0, 0, 0);
        }
    }

    // ---- diagonal tile kt == qt ----
    {
        __syncthreads();
        glds16(pk, lK); glds16(pk + 8 * DS, lK + 512);
        glds16(pg, lG); glds16(pg + 8 * Dm, lG + 512);
        glds16(pv, lV); glds16(pv + 8 * L,  lV + 512);
        __syncthreads();

        #pragma unroll
        for (int ni = 0; ni < 4; ++ni) {
            if (ni > wave) {
                *(unsigned long long*)&Pw[pwb + (((ni * 2 + pwc) ^ pxr) * 8)] = 0ull;
                continue;
            }
            bf16x8 kf0 = *(const bf16x8*)((const char*)K_l + rb + swz0 + ni * 2048);
            bf16x8 kf1 = *(const bf16x8*)((const char*)K_l + rb + swz1 + ni * 2048);
            bf16x8 gb0 = *(const bf16x8*)((const char*)G_l + rb + swz0 + ni * 2048);
            bf16x8 gb1 = *(const bf16x8*)((const char*)G_l + rb + swz1 + ni * 2048);
            f32x4 a = (f32x4){0.f, 0.f, 0.f, 0.f};
            a = __builtin_amdgcn_mfma_f32_16x16x32_bf16(kf0, qf[0], a, 0, 0, 0);
            a = __builtin_amdgcn_mfma_f32_16x16x32_bf16(gb0, gf[0], a, 0, 0, 0);
            a = __builtin_amdgcn_mfma_f32_16x16x32_bf16(kf1, qf[1], a, 0, 0, 0);
            a = __builtin_amdgcn_mfma_f32_16x16x32_bf16(gb1, gf[1], a, 0, 0, 0);
            float e0, e1, e2, e3;
            if (ni < wave) {
                e0 = exp2f(a[0]); e1 = exp2f(a[1]);
                e2 = exp2f(a[2]); e3 = exp2f(a[3]);
            } else {
                e0 = (quad * 4 + 0 <= l16) ? exp2f(a[0]) : 0.f;
                e1 = (quad * 4 + 1 <= l16) ? exp2f(a[1]) : 0.f;
                e2 = (quad * 4 + 2 <= l16) ? exp2f(a[2]) : 0.f;
                e3 = (quad * 4 + 3 <= l16) ? exp2f(a[3]) : 0.f;
            }
            lsum += (e0 + e1) + (e2 + e3);
            unsigned int p01 = pack2bf(e0, e1), p23 = pack2bf(e2, e3);
            *(unsigned long long*)&Pw[pwb + (((ni * 2 + pwc) ^ pxr) * 8)] =
                ((unsigned long long)p23 << 32) | p01;
        }
        asm volatile("s_waitcnt lgkmcnt(0)" ::: "memory");

        bf16x8 pa[2];
        #pragma unroll
        for (int c = 0; c < 2; ++c)
            pa[c] = *(const bf16x8*)&Pw[l16 * 64 + (((c * 4 + quad) ^ pxr) * 8)];
        #pragma unroll
        for (int nd = 0; nd < 4; ++nd) {
            bf16x8 vf0 = *(const bf16x8*)((const char*)V_l + rb + swz0 + nd * 2048);
            bf16x8 vf1 = *(const bf16x8*)((const char*)V_l + rb + swz1 + nd * 2048);
            o[nd] = __builtin_amdgcn_mfma_f32_16x16x32_bf16(pa[0], vf0, o[nd], 0, 0, 0);
            o[nd] = __builtin_amdgcn_mfma_f32_16x16x32_bf16(pa[1], vf1, o[nd], 0, 0, 0);
        }
    }

    float rs = lsum;
    rs += __shfl_xor(rs, 16);
    rs += __shfl_xor(rs, 32);
    #pragma unroll
    for (int r = 0; r < 4; ++r) {
        float inv = 1.f / __shfl(rs, (lane & 48) | (quad * 4 + r));
        int row = qt * 64 + wave * 16 + quad * 4 + r;
        #pragma unroll
        for (int nd = 0; nd < 4; ++nd)
            y[(size_t)(b * L + row) * Dm + h * 64 + nd * 16 + l16] =
                f2bf(o[nd][r] * inv);
    }
}

// ---------------------------------------------------------------------------
extern "C" void kernel_launch(void* const* d_in, const int* in_sizes, int n_in,
                              void* d_out, int out_size, void* d_ws, size_t ws_size,
                              hipStream_t stream) {
    const float* x     = (const float*)d_in[0];
    const float* q_g   = (const float*)d_in[1];
    const float* k_g   = (const float*)d_in[2];
    const float* W_qkv = (const float*)d_in[3];
    const float* W_out = (const float*)d_in[4];
    float* out = (float*)d_out;
    unsigned short* ws = (unsigned short*)d_ws;

    unsigned short* qk_ws = ws;                  // [4096][2048]  Q|K
    unsigned short* y_ws  = ws + 8388608;        // [4096][1024]
    unsigned short* wtq   = ws + 12582912;       // [3072][1024]
    unsigned short* wto   = ws + 15728640;       // [1024][1024]
    unsigned short* kg_bf = ws + 16777216;       // [4096][1024]
    unsigned short* x_bf  = ws + 20971520;       // [4096][1024]
    unsigned short* vt_bf = ws + 25165824;       // [32][64][2048]

    dim3 blk(256);
    prep_all<<<5120, blk, 0, stream>>>(x, x_bf, k_g, kg_bf, W_qkv, wtq, W_out, wto);
    gemm_qkv<<<dim3(24, 32), blk, 0, stream>>>(x_bf, wtq, qk_ws, vt_bf);
    attn7<<<dim3(32, 32), blk, 0, stream>>>(qk_ws, q_g, kg_bf, vt_bf, y_ws);
    gemm_n64<<<dim3(16, 32), blk, 0, stream>>>(y_ws, wto, out);
}